// Round 1
// baseline (310.019 us; speedup 1.0000x reference)
//
#include <hip/hip_runtime.h>

// Problem constants (from reference): S=56, B=5, C=20, N=128
constexpr int S_   = 56;
constexpr int B_   = 5;
constexpr int C_   = 20;
constexpr int N_   = 128;
constexpr int CELLS = N_ * S_ * S_;   // 401408
constexpr int PSTR  = B_ * (C_ + 5);  // 125 floats per cell (predicts)
constexpr int TSTR  = C_ + 5;         // 25 floats per cell (targets)

__global__ __launch_bounds__(256) void yolo_loss_kernel(
    const float* __restrict__ pred,
    const float* __restrict__ targ,
    const float* __restrict__ anch,   // [B,2]
    float* __restrict__ out)
{
    const int cell = blockIdx.x * 256 + threadIdx.x;
    float local = 0.f;

    if (cell < CELLS) {
        const float* p = pred + (long)cell * PSTR;
        const float* t = targ + (long)cell * TSTR;

        // Load all 25 target floats (all are used).
        float tc[TSTR];
        #pragma unroll
        for (int k = 0; k < TSTR; ++k) tc[k] = t[k];

        const float tcx = tc[C_ + 1], tcy = tc[C_ + 2];
        const float tw  = tc[C_ + 3], th  = tc[C_ + 4];
        const float tx0 = tcx - 0.5f * tw, ty0 = tcy - 0.5f * th;
        const float tx1 = tcx + 0.5f * tw, ty1 = tcy + 0.5f * th;
        const float area_t = tw * th;

        float best_iou = -1.f;
        int   best_b = 0;
        float bcx = 0.f, bcy = 0.f, bw = 0.f, bh = 0.f;

        #pragma unroll
        for (int b = 0; b < B_; ++b) {
            // raw box params of anchor b
            const float rcx = p[b * TSTR + C_ + 1];
            const float rcy = p[b * TSTR + C_ + 2];
            const float rw  = p[b * TSTR + C_ + 3];
            const float rh  = p[b * TSTR + C_ + 4];

            const float cx = __builtin_amdgcn_rcpf(1.f + __expf(-rcx)); // sigmoid
            const float cy = __builtin_amdgcn_rcpf(1.f + __expf(-rcy));
            const float w  = __expf(rw) * anch[2 * b];
            const float h  = __expf(rh) * anch[2 * b + 1];

            const float x0 = cx - 0.5f * w, y0 = cy - 0.5f * h;
            const float x1 = cx + 0.5f * w, y1 = cy + 0.5f * h;

            float wi = fminf(x1, tx1) - fmaxf(x0, tx0);
            float hi = fminf(y1, ty1) - fmaxf(y0, ty0);
            wi = fmaxf(wi, 0.f);
            hi = fmaxf(hi, 0.f);
            const float inter = wi * hi;
            // area_p = w*h exactly (box round-trips cxcywh->xyxy)
            const float iou = inter * __builtin_amdgcn_rcpf(w * h + area_t - inter);

            // jnp.argmax keeps the FIRST max -> strict '>'
            if (iou > best_iou) {
                best_iou = iou; best_b = b;
                bcx = cx; bcy = cy; bw = w; bh = h;
            }
        }

        const float* pb = p + best_b * TSTR;

        // class SSE (pbest[...,0] is scaled by best_idx per reference)
        float acc = 0.f;
        #pragma unroll
        for (int k = 0; k < C_; ++k) {
            float v = pb[k];
            if (k == 0) v *= (float)best_b;
            const float d = v - tc[k];
            acc = fmaf(d, d, acc);
        }

        // xy SSE (transformed)
        float d;
        d = bcx - tcx; acc = fmaf(d, d, acc);
        d = bcy - tcy; acc = fmaf(d, d, acc);

        // wh SSE: sign(x)*sqrt(|x|+1e-6); bw,bh > 0 always
        d = sqrtf(bw + 1e-6f) - tw; acc = fmaf(d, d, acc);
        d = sqrtf(bh + 1e-6f) - th; acc = fmaf(d, d, acc);

        // obj / noobj share (pbest[20]-t[20])^2
        const float e    = tc[C_];
        const float ne   = 1.f - e;
        const float dobj = pb[C_] - e;
        local = e * e * acc + (e * e + ne * ne) * (dobj * dobj);
    }

    // wave(64) shuffle reduction
    #pragma unroll
    for (int off = 32; off > 0; off >>= 1)
        local += __shfl_down(local, off, 64);

    __shared__ float wsum[4];
    const int lane = threadIdx.x & 63;
    const int wid  = threadIdx.x >> 6;
    if (lane == 0) wsum[wid] = local;
    __syncthreads();
    if (threadIdx.x == 0)
        atomicAdd(out, wsum[0] + wsum[1] + wsum[2] + wsum[3]);
}

extern "C" void kernel_launch(void* const* d_in, const int* in_sizes, int n_in,
                              void* d_out, int out_size, void* d_ws, size_t ws_size,
                              hipStream_t stream) {
    const float* pred = (const float*)d_in[0];   // (N,S,S,B,C+5) f32
    const float* targ = (const float*)d_in[1];   // (N,S,S,C+5)   f32
    const float* anch = (const float*)d_in[2];   // (B,2)         f32
    float* out = (float*)d_out;

    // d_out is poisoned before timed launches; atomics need a zero base.
    hipMemsetAsync(out, 0, (size_t)out_size * sizeof(float), stream);

    const int blocks = (CELLS + 255) / 256;      // 1568, exact
    yolo_loss_kernel<<<blocks, 256, 0, stream>>>(pred, targ, anch, out);
}

// Round 2
// 308.600 us; speedup vs baseline: 1.0046x; 1.0046x over previous
//
#include <hip/hip_runtime.h>

// Problem constants (from reference): S=56, B=5, C=20, N=128
constexpr int S_   = 56;
constexpr int B_   = 5;
constexpr int C_   = 20;
constexpr int N_   = 128;
constexpr int CELLS = N_ * S_ * S_;   // 401408
constexpr int PSTR  = B_ * (C_ + 5);  // 125 floats per cell (predicts)
constexpr int TSTR  = C_ + 5;         // 25 floats per cell (targets)

// Unaligned-tolerant 16-byte load (gfx950 supports unaligned global dwordx4;
// all our offsets are 4 B-aligned). memcpy avoids alignment UB.
struct F4 { float a, b, c, d; };
__device__ __forceinline__ F4 ld4(const float* __restrict__ p) {
    F4 r;
    __builtin_memcpy(&r, p, 16);
    return r;
}

__global__ __launch_bounds__(256) void yolo_loss_kernel(
    const float* __restrict__ pred,
    const float* __restrict__ targ,
    const float* __restrict__ anch,   // [B,2]
    float* __restrict__ out)
{
    const int cell = blockIdx.x * 256 + threadIdx.x;
    float local = 0.f;

    if (cell < CELLS) {
        const float* p = pred + (long)cell * PSTR;
        const float* t = targ + (long)cell * TSTR;

        // ---- Issue all independent loads up front (MLP) ----
        // Targets: 25 floats = 6 x float4 + 1 scalar
        F4 tv[6];
        #pragma unroll
        for (int i = 0; i < 6; ++i) tv[i] = ld4(t + 4 * i);
        const float t24 = t[24];

        // Box params of each anchor: 4 contiguous floats at dword 21..24
        F4 box[B_];
        #pragma unroll
        for (int b = 0; b < B_; ++b) box[b] = ld4(p + b * TSTR + C_ + 1);

        float tc[TSTR];
        #pragma unroll
        for (int i = 0; i < 6; ++i) {
            tc[4 * i + 0] = tv[i].a; tc[4 * i + 1] = tv[i].b;
            tc[4 * i + 2] = tv[i].c; tc[4 * i + 3] = tv[i].d;
        }
        tc[24] = t24;

        const float tcx = tc[C_ + 1], tcy = tc[C_ + 2];
        const float tw  = tc[C_ + 3], th  = tc[C_ + 4];
        const float tx0 = tcx - 0.5f * tw, ty0 = tcy - 0.5f * th;
        const float tx1 = tcx + 0.5f * tw, ty1 = tcy + 0.5f * th;
        const float area_t = tw * th;

        float best_iou = -1.f;
        int   best_b = 0;
        float bcx = 0.f, bcy = 0.f, bw = 0.f, bh = 0.f;

        #pragma unroll
        for (int b = 0; b < B_; ++b) {
            const float cx = __builtin_amdgcn_rcpf(1.f + __expf(-box[b].a)); // sigmoid
            const float cy = __builtin_amdgcn_rcpf(1.f + __expf(-box[b].b));
            const float w  = __expf(box[b].c) * anch[2 * b];
            const float h  = __expf(box[b].d) * anch[2 * b + 1];

            const float x0 = cx - 0.5f * w, y0 = cy - 0.5f * h;
            const float x1 = cx + 0.5f * w, y1 = cy + 0.5f * h;

            float wi = fminf(x1, tx1) - fmaxf(x0, tx0);
            float hi = fminf(y1, ty1) - fmaxf(y0, ty0);
            wi = fmaxf(wi, 0.f);
            hi = fmaxf(hi, 0.f);
            const float inter = wi * hi;
            const float iou = inter * __builtin_amdgcn_rcpf(w * h + area_t - inter);

            // jnp.argmax keeps FIRST max -> strict '>'
            const bool better = iou > best_iou;
            best_iou = better ? iou : best_iou;
            best_b   = better ? b   : best_b;
            bcx = better ? cx : bcx;
            bcy = better ? cy : bcy;
            bw  = better ? w  : bw;
            bh  = better ? h  : bh;
        }

        // Best anchor's class+obj block: 21 floats = 5 x float4 + 1 scalar.
        // (These lines are already in L1 from the box loads.)
        const float* pb = p + best_b * TSTR;
        F4 cv[5];
        #pragma unroll
        for (int i = 0; i < 5; ++i) cv[i] = ld4(pb + 4 * i);
        const float pobj = pb[C_];

        float cls[C_];
        #pragma unroll
        for (int i = 0; i < 5; ++i) {
            cls[4 * i + 0] = cv[i].a; cls[4 * i + 1] = cv[i].b;
            cls[4 * i + 2] = cv[i].c; cls[4 * i + 3] = cv[i].d;
        }

        // class SSE (pbest[...,0] scaled by best_idx per reference)
        float acc = 0.f;
        #pragma unroll
        for (int k = 0; k < C_; ++k) {
            float v = cls[k];
            if (k == 0) v *= (float)best_b;
            const float d = v - tc[k];
            acc = fmaf(d, d, acc);
        }

        // xy SSE (transformed)
        float d;
        d = bcx - tcx; acc = fmaf(d, d, acc);
        d = bcy - tcy; acc = fmaf(d, d, acc);

        // wh SSE: sign(x)*sqrt(|x|+1e-6); bw,bh > 0 always
        d = sqrtf(bw + 1e-6f) - tw; acc = fmaf(d, d, acc);
        d = sqrtf(bh + 1e-6f) - th; acc = fmaf(d, d, acc);

        // obj / noobj share (pbest[20]-t[20])^2
        const float e    = tc[C_];
        const float ne   = 1.f - e;
        const float dobj = pobj - e;
        local = e * e * acc + (e * e + ne * ne) * (dobj * dobj);
    }

    // wave(64) shuffle reduction
    #pragma unroll
    for (int off = 32; off > 0; off >>= 1)
        local += __shfl_down(local, off, 64);

    __shared__ float wsum[4];
    const int lane = threadIdx.x & 63;
    const int wid  = threadIdx.x >> 6;
    if (lane == 0) wsum[wid] = local;
    __syncthreads();
    if (threadIdx.x == 0)
        atomicAdd(out, wsum[0] + wsum[1] + wsum[2] + wsum[3]);
}

extern "C" void kernel_launch(void* const* d_in, const int* in_sizes, int n_in,
                              void* d_out, int out_size, void* d_ws, size_t ws_size,
                              hipStream_t stream) {
    const float* pred = (const float*)d_in[0];   // (N,S,S,B,C+5) f32
    const float* targ = (const float*)d_in[1];   // (N,S,S,C+5)   f32
    const float* anch = (const float*)d_in[2];   // (B,2)         f32
    float* out = (float*)d_out;

    // d_out is poisoned before timed launches; atomics need a zero base.
    hipMemsetAsync(out, 0, (size_t)out_size * sizeof(float), stream);

    const int blocks = (CELLS + 255) / 256;      // 1568, exact
    yolo_loss_kernel<<<blocks, 256, 0, stream>>>(pred, targ, anch, out);
}

// Round 3
// 302.399 us; speedup vs baseline: 1.0252x; 1.0205x over previous
//
#include <hip/hip_runtime.h>

// Problem constants (from reference): S=56, B=5, C=20, N=128
constexpr int S_   = 56;
constexpr int B_   = 5;
constexpr int C_   = 20;
constexpr int N_   = 128;
constexpr int CELLS = N_ * S_ * S_;   // 401408
constexpr int PSTR  = B_ * (C_ + 5);  // 125 floats per cell (predicts)
constexpr int TSTR  = C_ + 5;         // 25 floats per cell (targets)

constexpr int CPB    = 64;            // cells per block (= 1 wave, 1 cell/thread)
constexpr int NBLK   = CELLS / CPB;   // 6272, exact
constexpr int PRED_B = CPB * PSTR * 4;  // 32000 bytes, contiguous in global
constexpr int TARG_B = CPB * TSTR * 4;  // 6400 bytes, contiguous in global

constexpr int NBUCKET       = 64;
constexpr int BUCKET_STRIDE = 32;     // floats -> 128 B apart, no line sharing

// async global->LDS, 16 B per lane. LDS dest = wave-uniform base + lane*16.
__device__ __forceinline__ void gload_lds16(const char* g, char* l) {
    __builtin_amdgcn_global_load_lds(
        (const __attribute__((address_space(1))) void*)g,
        (__attribute__((address_space(3))) void*)l,
        16, 0, 0);
}

__global__ __launch_bounds__(64) void yolo_loss_kernel(
    const float* __restrict__ pred,
    const float* __restrict__ targ,
    const float* __restrict__ anch,   // [B,2]
    float* __restrict__ buckets)      // [NBUCKET * BUCKET_STRIDE] in d_ws
{
    __shared__ char lds[PRED_B + TARG_B];   // 38400 B -> 4 blocks/CU

    const int lane  = threadIdx.x;          // 0..63
    const int cell0 = blockIdx.x * CPB;

    // ---- coalesced streaming stage: global -> LDS (1 KB per instruction) ----
    const char* gp = (const char*)(pred + (size_t)cell0 * PSTR);  // 32000 B
    const char* gt = (const char*)(targ + (size_t)cell0 * TSTR);  //  6400 B

    #pragma unroll
    for (int it = 0; it < 31; ++it)                       // 31 * 1024 = 31744
        gload_lds16(gp + it * 1024 + lane * 16, lds + it * 1024);
    #pragma unroll
    for (int it = 0; it < 6; ++it)                        // 6 * 1024 = 6144
        gload_lds16(gt + it * 1024 + lane * 16, lds + PRED_B + it * 1024);
    if (lane < 16) {                                      // 256 B tails
        gload_lds16(gp + 31744 + lane * 16, lds + 31744);
        gload_lds16(gt + 6144  + lane * 16, lds + PRED_B + 6144);
    }

    // anchors: 10 uniform floats, L1-resident broadcast
    float aw[B_], ah[B_];
    #pragma unroll
    for (int b = 0; b < B_; ++b) { aw[b] = anch[2 * b]; ah[b] = anch[2 * b + 1]; }

    __syncthreads();   // drains vmcnt(0) -> LDS valid

    // ---- compute: one cell per thread, all operands in LDS ----
    const float* pc = (const float*)lds + (size_t)lane * PSTR;            // my cell's 125 preds
    const float* tp = (const float*)(lds + PRED_B) + (size_t)lane * TSTR; // my cell's 25 targets

    const float tcx = tp[C_ + 1], tcy = tp[C_ + 2];
    const float tw  = tp[C_ + 3], th  = tp[C_ + 4];
    const float tx0 = tcx - 0.5f * tw, ty0 = tcy - 0.5f * th;
    const float tx1 = tcx + 0.5f * tw, ty1 = tcy + 0.5f * th;
    const float area_t = tw * th;

    float best_iou = -1.f;
    int   best_b = 0;
    float bcx = 0.f, bcy = 0.f, bw = 0.f, bh = 0.f;

    #pragma unroll
    for (int b = 0; b < B_; ++b) {
        const float rcx = pc[b * TSTR + C_ + 1];
        const float rcy = pc[b * TSTR + C_ + 2];
        const float rw  = pc[b * TSTR + C_ + 3];
        const float rh  = pc[b * TSTR + C_ + 4];

        const float cx = __builtin_amdgcn_rcpf(1.f + __expf(-rcx)); // sigmoid
        const float cy = __builtin_amdgcn_rcpf(1.f + __expf(-rcy));
        const float w  = __expf(rw) * aw[b];
        const float h  = __expf(rh) * ah[b];

        const float x0 = cx - 0.5f * w, y0 = cy - 0.5f * h;
        const float x1 = cx + 0.5f * w, y1 = cy + 0.5f * h;

        float wi = fminf(x1, tx1) - fmaxf(x0, tx0);
        float hi = fminf(y1, ty1) - fmaxf(y0, ty0);
        wi = fmaxf(wi, 0.f);
        hi = fmaxf(hi, 0.f);
        const float inter = wi * hi;
        const float iou = inter * __builtin_amdgcn_rcpf(w * h + area_t - inter);

        // jnp.argmax keeps FIRST max -> strict '>'
        const bool better = iou > best_iou;
        best_iou = better ? iou : best_iou;
        best_b   = better ? b   : best_b;
        bcx = better ? cx : bcx;
        bcy = better ? cy : bcy;
        bw  = better ? w  : bw;
        bh  = better ? h  : bh;
    }

    const float* pb = pc + best_b * TSTR;   // divergent LDS offset — fine

    // class SSE (pbest[...,0] scaled by best_idx per reference)
    float acc = 0.f;
    #pragma unroll
    for (int k = 0; k < C_; ++k) {
        float v = pb[k];
        if (k == 0) v *= (float)best_b;
        const float d = v - tp[k];
        acc = fmaf(d, d, acc);
    }

    // xy SSE (transformed)
    float d;
    d = bcx - tcx; acc = fmaf(d, d, acc);
    d = bcy - tcy; acc = fmaf(d, d, acc);

    // wh SSE: sign(x)*sqrt(|x|+1e-6); bw,bh > 0 always
    d = sqrtf(bw + 1e-6f) - tw; acc = fmaf(d, d, acc);
    d = sqrtf(bh + 1e-6f) - th; acc = fmaf(d, d, acc);

    // obj / noobj share (pbest[20]-t[20])^2
    const float e    = tp[C_];
    const float ne   = 1.f - e;
    const float dobj = pb[C_] - e;
    float local = e * e * acc + (e * e + ne * ne) * (dobj * dobj);

    // wave(64) shuffle reduction, then one atomic per block into a bucket
    #pragma unroll
    for (int off = 32; off > 0; off >>= 1)
        local += __shfl_down(local, off, 64);

    if (lane == 0)
        atomicAdd(&buckets[(blockIdx.x & (NBUCKET - 1)) * BUCKET_STRIDE], local);
}

__global__ __launch_bounds__(64) void finalize_kernel(
    const float* __restrict__ buckets, float* __restrict__ out)
{
    float v = buckets[threadIdx.x * BUCKET_STRIDE];
    #pragma unroll
    for (int off = 32; off > 0; off >>= 1)
        v += __shfl_down(v, off, 64);
    if (threadIdx.x == 0) out[0] = v;
}

extern "C" void kernel_launch(void* const* d_in, const int* in_sizes, int n_in,
                              void* d_out, int out_size, void* d_ws, size_t ws_size,
                              hipStream_t stream) {
    const float* pred = (const float*)d_in[0];   // (N,S,S,B,C+5) f32
    const float* targ = (const float*)d_in[1];   // (N,S,S,C+5)   f32
    const float* anch = (const float*)d_in[2];   // (B,2)         f32
    float* out     = (float*)d_out;
    float* buckets = (float*)d_ws;               // 64 buckets, 128 B apart

    // d_ws is poisoned 0xAA before every timed launch — zero our buckets.
    hipMemsetAsync(buckets, 0, NBUCKET * BUCKET_STRIDE * sizeof(float), stream);

    yolo_loss_kernel<<<NBLK, CPB, 0, stream>>>(pred, targ, anch, buckets);
    finalize_kernel<<<1, 64, 0, stream>>>(buckets, out);
}